// Round 3
// baseline (250.642 us; speedup 1.0000x reference)
//
#include <hip/hip_runtime.h>

// Two threads per 3-qubit state vector. Thread u: state s = u>>1, half h = u&1,
// holding amps 4h..4h+3 (amp index = q0*4 + q1*2 + q2, so h == q0).
// Circuit: H(q0),H(q1),RX(t0,q0),RX(t1,q1),CNOT(q0->q2).
// Fused M(q) = RX(q)*H = k*[[c-is, c+is],[c-is, -(c+is)]]:
//   a' = p*a + q*b ; b' = p*a - q*b, p = k(c-is), q = k(c+is), k = 1/sqrt(2).
// q0 gate couples lane pairs via __shfl_xor(.,1); q1 gate + CNOT are local.
// Output stores are NON-TEMPORAL: the 134 MB output stream is never re-read
// in the timed region, and letting it allocate in L2/L3 evicts the 256 MiB of
// inputs that otherwise stay L3-resident across graph replays (R1: FETCH 66MB).
using f4 = __attribute__((ext_vector_type(4))) float;

__global__ __launch_bounds__(256) void circuit_kernel(
    const f4* __restrict__ xr4,
    const f4* __restrict__ xi4,
    const float* __restrict__ theta,
    f4* __restrict__ o4,
    int N)  // N = 2*B half-states
{
    int u = blockIdx.x * blockDim.x + threadIdx.x;
    if (u >= N) return;
    const int h = u & 1;
    const float k = 0.70710678118654752440f;

    float c0, s0, c1, s1;
    __sincosf(theta[0] * 0.5f, &s0, &c0);
    __sincosf(theta[1] * 0.5f, &s1, &c1);

    // q0 multiplier for this lane: p for h=0, q for h=1
    const float mr = k * c0;
    const float mi = h ? (k * s0) : (-k * s0);

    // Perfectly coalesced loads: 16 B/lane, lane-contiguous. Keep cached (L3 reuse).
    f4 fr = xr4[u];
    f4 fi = xi4[u];
    float ar[4] = {fr.x, fr.y, fr.z, fr.w};
    float ai[4] = {fi.x, fi.y, fi.z, fi.w};

    // --- fused H+RX on qubit 0 (cross-lane) ---
    float lr[4], li[4], pr[4], pi[4];
#pragma unroll
    for (int j = 0; j < 4; ++j) {
        lr[j] = mr * ar[j] - mi * ai[j];
        li[j] = mr * ai[j] + mi * ar[j];
    }
#pragma unroll
    for (int j = 0; j < 4; ++j) {
        pr[j] = __shfl_xor(lr[j], 1, 64);
        pi[j] = __shfl_xor(li[j], 1, 64);
    }
#pragma unroll
    for (int j = 0; j < 4; ++j) {
        ar[j] = h ? (pr[j] - lr[j]) : (lr[j] + pr[j]);
        ai[j] = h ? (pi[j] - li[j]) : (li[j] + pi[j]);
    }

    // --- fused H+RX on qubit 1: pairs (j, j+2), local ---
    const float p1r = k * c1, p1i = -k * s1;
    const float q1r = k * c1, q1i = k * s1;
#pragma unroll
    for (int j = 0; j < 2; ++j) {
        float xr_ = p1r * ar[j]     - p1i * ai[j];
        float xi_ = p1r * ai[j]     + p1i * ar[j];
        float yr_ = q1r * ar[j + 2] - q1i * ai[j + 2];
        float yi_ = q1r * ai[j + 2] + q1i * ar[j + 2];
        ar[j]     = xr_ + yr_;  ai[j]     = xi_ + yi_;
        ar[j + 2] = xr_ - yr_;  ai[j + 2] = xi_ - yi_;
    }

    // --- CNOT (q0 ctrl, q2 tgt): h==1 swaps j0<->j1, j2<->j3; fold into store.
    int a = h ? 1 : 0, b = h ? 0 : 1, c = h ? 3 : 2, d = h ? 2 : 3;
    f4 o0 = {ar[a], ai[a], ar[b], ai[b]};
    f4 o1 = {ar[c], ai[c], ar[d], ai[d]};
    __builtin_nontemporal_store(o0, o4 + 2 * u);
    __builtin_nontemporal_store(o1, o4 + 2 * u + 1);
}

extern "C" void kernel_launch(void* const* d_in, const int* in_sizes, int n_in,
                              void* d_out, int out_size, void* d_ws, size_t ws_size,
                              hipStream_t stream) {
    const f4* xr4      = (const f4*)d_in[0];
    const f4* xi4      = (const f4*)d_in[1];
    const float* theta = (const float*)d_in[2];
    f4* o4 = (f4*)d_out;

    int N = in_sizes[0] / 4;  // B*8 floats / 4 = 2B half-states
    int block = 256;
    int grid = (N + block - 1) / block;
    circuit_kernel<<<grid, block, 0, stream>>>(xr4, xi4, theta, o4, N);
}